// Round 3
// baseline (2289.454 us; speedup 1.0000x reference)
//
#include <hip/hip_runtime.h>
#include <hip/hip_fp16.h>

#define BB 64
#define SS 1024
#define HD 256
#define GG 768   // 3*HD
#define NT 256   // threads per block (4 waves = 1 wave/SIMD -> 512-VGPR budget)

typedef _Float16 h2_t __attribute__((ext_vector_type(2)));
typedef _Float16 h8_t __attribute__((ext_vector_type(8)));

#define FDOT2(a, b, c) __builtin_amdgcn_fdot2((a), (b), (c), false)

__device__ __forceinline__ float sigm(float x) {
    return 1.0f / (1.0f + __expf(-x));
}
__device__ __forceinline__ float tanh_fast(float x) {
    float e = __expf(2.0f * fabsf(x));
    float t = 1.0f - 2.0f / (e + 1.0f);
    return copysignf(t, x);
}

// DPP quad_perm butterfly add: reduce 4 K-slice partials within a lane quad (VALU only).
__device__ __forceinline__ float quad_reduce(float x) {
    int t = __builtin_amdgcn_update_dpp(0, __float_as_int(x), 0xB1, 0xF, 0xF, true); // xor 1
    x += __int_as_float(t);
    t = __builtin_amdgcn_update_dpp(0, __float_as_int(x), 0x4E, 0xF, 0xF, true);     // xor 2
    x += __int_as_float(t);
    return x;
}

// Bank-skewed LDS layout for a 256-f16 vector (validated bit-exact in prior round):
// elem k -> byte (k>>6)*128 + ((((k>>3)&7) + 2*(k>>6)) & 7)*16 + (k&7)*2
__device__ __forceinline__ int swz256(int k) {
    int ksl = k >> 6;
    return ksl * 128 + ((((k >> 3) & 7) + 2 * ksl) & 7) * 16 + (k & 7) * 2;
}

// Thread (wv, r_=l>>2, sl=l&3) owns, for each gate gi in {r,z,n} and each q in 0..3,
// the K-slice [sl*64, sl*64+64) of weight row gi*256 + wv*64 + r_ + 16*q.
// 3*4*32 = 384 h2 regs, all statically indexed. Needs the 512-VGPR (1 wave/SIMD) budget.
__device__ __forceinline__ void load_w3(const float* W, int wv, int r_, int sl, h2_t w[3][4][32]) {
#pragma unroll
    for (int gi = 0; gi < 3; gi++) {
#pragma unroll
        for (int q = 0; q < 4; q++) {
            const float2* wr = (const float2*)(W + (size_t)(gi * 256 + wv * 64 + r_ + 16 * q) * 256 + sl * 64);
#pragma unroll
            for (int k = 0; k < 32; k++) {
                float2 f = wr[k];
                h2_t p; p.x = (_Float16)f.x; p.y = (_Float16)f.y;
                w[gi][q][k] = p;
            }
        }
    }
}

// 12 accumulator chains (3 gates x 4 quad-outputs) over this lane's 64-elem K-slice.
// 8 ds_read_b128 per lane, 384 fdot2. Skew (j+2*sl)&7 keeps the 4 slices in disjoint bank quads.
__device__ __forceinline__ void dot12(const char* tbase, int sl, const h2_t w[3][4][32], float acc[3][4]) {
    const char* base = tbase + sl * 128;
#pragma unroll
    for (int j = 0; j < 8; j++) {
        h8_t v = *(const h8_t*)(base + (((j + 2 * sl) & 7) << 4));
        h2_t p0, p1, p2, p3;
        p0.x = v[0]; p0.y = v[1];
        p1.x = v[2]; p1.y = v[3];
        p2.x = v[4]; p2.y = v[5];
        p3.x = v[6]; p3.y = v[7];
#pragma unroll
        for (int gi = 0; gi < 3; gi++) {
#pragma unroll
            for (int q = 0; q < 4; q++) {
                acc[gi][q] = FDOT2(w[gi][q][4 * j + 0], p0, acc[gi][q]);
                acc[gi][q] = FDOT2(w[gi][q][4 * j + 1], p1, acc[gi][q]);
                acc[gi][q] = FDOT2(w[gi][q][4 * j + 2], p2, acc[gi][q]);
                acc[gi][q] = FDOT2(w[gi][q][4 * j + 3], p3, acc[gi][q]);
            }
        }
    }
}

// statically-indexed quad select (no runtime array indexing -> no scratch)
__device__ __forceinline__ float pick4(const float a[4], int sl) {
    return sl == 0 ? a[0] : sl == 1 ? a[1] : sl == 2 ? a[2] : a[3];
}

// producer/consumer flags: per-(role,batch) monotone chunk counters, 64B-padded
__device__ __forceinline__ void wait_ge(unsigned* f, unsigned v) {
    if (threadIdx.x == 0) {
        while (__hip_atomic_load(f, __ATOMIC_RELAXED, __HIP_MEMORY_SCOPE_AGENT) < v)
            __builtin_amdgcn_s_sleep(2);
        (void)__hip_atomic_load(f, __ATOMIC_ACQUIRE, __HIP_MEMORY_SCOPE_AGENT);
    }
    __syncthreads();
}
__device__ __forceinline__ void publish(unsigned* f, unsigned v) {
    __syncthreads();   // drains all waves' vmcnt (compiler emits waitcnt before barrier)
    if (threadIdx.x == 0)
        __hip_atomic_store(f, v, __ATOMIC_RELEASE, __HIP_MEMORY_SCOPE_AGENT);
}

// ---------------------------------------------------------------------------
// Persistent 4-stage pipeline: 256 blocks = 4 roles x 64 batches, 256 thr/block.
// role 0: P0  inputs -> xg0 ring          role 2: R0  xg0 -> h1 (cat)
// role 1: P1  h1(cat) -> xg1 ring         role 3: R1  xg1 -> h2 (out + cat)
// Each thread owns output i = wv*64 + (l>>2) + 16*(l&3): all 3 gate rows register-
// resident (384 VGPRs, 1 wave/SIMD budget). Recurrence: h ping-pong in LDS,
// ONE barrier per step, h_prev in register, no inter-gate LDS round-trip.
// ---------------------------------------------------------------------------
__global__ __launch_bounds__(NT, 1) void gru_pipe(
    const float* __restrict__ X,
    const float* __restrict__ Wih0, const float* __restrict__ bih0,
    const float* __restrict__ Whh0, const float* __restrict__ bhh0,
    const float* __restrict__ Wih1, const float* __restrict__ bih1,
    const float* __restrict__ Whh1, const float* __restrict__ bhh1,
    float* __restrict__ h2out, float* __restrict__ cat,
    float* __restrict__ ring0, float* __restrict__ ring1,
    unsigned* __restrict__ prog, int CT, int NS, int NC)
{
    __shared__ h8_t xs[2048];   // 32 KB: producer x staging / recurrence h ping-pong (2x512B)

    const int role = blockIdx.x >> 6;
    const int b    = blockIdx.x & 63;
    const int g    = threadIdx.x;
    const int wv   = g >> 6;
    const int l    = g & 63;
    const int r_   = l >> 2;
    const int sl   = l & 3;
    const int i    = wv * 64 + r_ + 16 * sl;   // owned output index in [0,256)

    unsigned* f_p0 = prog + (0 * 64 + b) * 16;
    unsigned* f_p1 = prog + (1 * 64 + b) * 16;
    unsigned* f_r0 = prog + (2 * 64 + b) * 16;
    unsigned* f_r1 = prog + (3 * 64 + b) * 16;

    h2_t w[3][4][32];

    if (role == 0 || role == 1) {
        // ------- projection producer -------
        const float* Wp   = (role == 0) ? Wih0 : Wih1;
        const float* bp   = (role == 0) ? bih0 : bih1;
        const float* Xs   = (role == 0) ? X : cat;
        const int xstride = (role == 0) ? 256 : 512;
        float* ringo      = (role == 0) ? ring0 : ring1;
        unsigned* f_up    = (role == 0) ? nullptr : f_r0;   // P1 waits for h1 chunk
        unsigned* f_cons  = (role == 0) ? f_r0 : f_r1;      // ring reuse guard
        unsigned* f_out   = (role == 0) ? f_p0 : f_p1;

        load_w3(Wp, wv, r_, sl, w);
        const float b0 = bp[i], b1 = bp[256 + i], b2 = bp[512 + i];
        char* xb = (char*)xs;

        for (int c = 0; c < NC; c++) {
            if (f_up) wait_ge(f_up, c + 1);
            if (c >= NS) wait_ge(f_cons, c - NS + 1);
            const int t0 = c * CT;
            for (int idx = g; idx < CT * 256; idx += NT) {
                int tt = idx >> 8, k = idx & 255;
                *(_Float16*)(xb + tt * 512 + swz256(k)) =
                    (_Float16)Xs[((size_t)b * SS + t0 + tt) * xstride + k];
            }
            __syncthreads();
            float* ro = ringo + ((size_t)b * NS + (c % NS)) * ((size_t)CT * GG);
            for (int tt = 0; tt < CT; tt++) {
                float acc[3][4] = {};
                dot12(xb + tt * 512, sl, w, acc);
                float ar = quad_reduce(acc[0][0]), a1 = quad_reduce(acc[0][1]),
                      a2 = quad_reduce(acc[0][2]), a3 = quad_reduce(acc[0][3]);
                float zr = quad_reduce(acc[1][0]), z1 = quad_reduce(acc[1][1]),
                      z2 = quad_reduce(acc[1][2]), z3 = quad_reduce(acc[1][3]);
                float nr = quad_reduce(acc[2][0]), n1 = quad_reduce(acc[2][1]),
                      n2 = quad_reduce(acc[2][2]), n3 = quad_reduce(acc[2][3]);
                float fa[4] = {ar, a1, a2, a3};
                float fz[4] = {zr, z1, z2, z3};
                float fn[4] = {nr, n1, n2, n3};
                float* rt = ro + (size_t)tt * GG;
                rt[i]       = pick4(fa, sl) + b0;
                rt[256 + i] = pick4(fz, sl) + b1;
                rt[512 + i] = pick4(fn, sl) + b2;
            }
            publish(f_out, c + 1);   // its syncthreads also guards LDS reuse
        }
    } else {
        // ------- recurrence -------
        const float* Wp    = (role == 2) ? Whh0 : Whh1;
        const float* bp    = (role == 2) ? bhh0 : bhh1;
        const float* ringi = (role == 2) ? ring0 : ring1;
        unsigned* f_in  = (role == 2) ? f_p0 : f_p1;
        unsigned* f_out = (role == 2) ? f_r0 : f_r1;
        float* outA   = (role == 2) ? cat : h2out;
        int   strideA = (role == 2) ? 512 : 256;
        float* outB   = (role == 2) ? nullptr : (cat + 256);   // stride 512

        load_w3(Wp, wv, r_, sl, w);
        const float b0 = bp[i], b1 = bp[256 + i], b2 = bp[512 + i];
        char* xb = (char*)xs;
        // ping-pong h buffers (512B each, swizzled); write slots precomputed
        _Float16* hws0 = (_Float16*)(xb + swz256(i));
        _Float16* hws1 = (_Float16*)(xb + 512 + swz256(i));
        float hprev = 0.0f;

        ((unsigned short*)xs)[g] = 0;   // zero buf0 (h0 = 0); zeros are swizzle-invariant
        __syncthreads();

        for (int c = 0; c < NC; c++) {
            wait_ge(f_in, c + 1);
            const float* xgp = ringi + ((size_t)b * NS + (c % NS)) * ((size_t)CT * GG);
            float xr = xgp[i], xz = xgp[256 + i], xn = xgp[512 + i];
            for (int tt = 0; tt < CT; tt++) {
                // prefetch next step's ring values (wave-uniform predicate)
                float xr2 = 0.f, xz2 = 0.f, xn2 = 0.f;
                if (tt + 1 < CT) {
                    const float* nx = xgp + (size_t)(tt + 1) * GG;
                    xr2 = nx[i]; xz2 = nx[256 + i]; xn2 = nx[512 + i];
                }
                float acc[3][4] = {};
                dot12(xb + ((tt & 1) << 9), sl, w, acc);   // read h from buf[tt&1]
                float a0 = quad_reduce(acc[0][0]), a1 = quad_reduce(acc[0][1]),
                      a2 = quad_reduce(acc[0][2]), a3 = quad_reduce(acc[0][3]);
                float c0 = quad_reduce(acc[1][0]), c1 = quad_reduce(acc[1][1]),
                      c2 = quad_reduce(acc[1][2]), c3 = quad_reduce(acc[1][3]);
                float d0 = quad_reduce(acc[2][0]), d1 = quad_reduce(acc[2][1]),
                      d2 = quad_reduce(acc[2][2]), d3 = quad_reduce(acc[2][3]);
                float fa[4] = {a0, a1, a2, a3};
                float fc[4] = {c0, c1, c2, c3};
                float fd[4] = {d0, d1, d2, d3};
                float hr = pick4(fa, sl) + b0;
                float hz = pick4(fc, sl) + b1;
                float hn = pick4(fd, sl) + b2;
                float rg = sigm(xr + hr);
                float zg = sigm(xz + hz);
                float ng = tanh_fast(xn + rg * hn);
                float hnew = (1.0f - zg) * ng + zg * hprev;
                hprev = hnew;
                // write h to the OTHER buffer -> no read/write hazard, one barrier/step
                _Float16* hw = (tt & 1) ? hws0 : hws1;
                *hw = (_Float16)hnew;
                size_t t = (size_t)(c * CT + tt);
                outA[((size_t)b * SS + t) * strideA + i] = hnew;
                if (outB) outB[((size_t)b * SS + t) * 512 + i] = hnew;
                __syncthreads();
                xr = xr2; xz = xz2; xn = xn2;
            }
            publish(f_out, c + 1);
        }
    }
}

// ---------------------------------------------------------------------------
extern "C" void kernel_launch(void* const* d_in, const int* in_sizes, int n_in,
                              void* d_out, int out_size, void* d_ws, size_t ws_size,
                              hipStream_t stream)
{
    const float* inputs = (const float*)d_in[0];
    const float* W_ih0  = (const float*)d_in[1];
    const float* W_hh0  = (const float*)d_in[2];
    const float* b_ih0  = (const float*)d_in[3];
    const float* b_hh0  = (const float*)d_in[4];
    const float* W_ih1  = (const float*)d_in[5];
    const float* W_hh1  = (const float*)d_in[6];
    const float* b_ih1  = (const float*)d_in[7];
    const float* b_hh1  = (const float*)d_in[8];

    float* h2out = (float*)d_out;                    // [B,S,256]
    float* cat   = h2out + (size_t)BB * SS * HD;     // [B,S,512] = [h1 | h2]

    unsigned char* ws = (unsigned char*)d_ws;
    unsigned* prog = (unsigned*)ws;
    const size_t FLAG_BYTES = 4 * 64 * 16 * sizeof(unsigned);   // 64B-padded counters
    size_t avail = ws_size > FLAG_BYTES ? ws_size - FLAG_BYTES : 0;

    // pick chunk length CT and ring slots NS to fit workspace
    int CT = 64, NS = 0;
    for (;;) {
        size_t slot = (size_t)BB * CT * GG * sizeof(float);   // one slot, one ring
        size_t m = slot ? avail / (2 * slot) : 0;
        int nc = SS / CT;
        NS = (int)(m < (size_t)nc ? m : (size_t)nc);
        if (NS >= 2 || CT == 8) break;
        CT >>= 1;
    }
    if (NS < 1) NS = 1;
    int NC = SS / CT;

    float* ring0 = (float*)(ws + FLAG_BYTES);
    float* ring1 = ring0 + (size_t)BB * NS * CT * GG;

    hipMemsetAsync(prog, 0, FLAG_BYTES, stream);
    gru_pipe<<<256, NT, 0, stream>>>(inputs,
                                     W_ih0, b_ih0, W_hh0, b_hh0,
                                     W_ih1, b_ih1, W_hh1, b_hh1,
                                     h2out, cat, ring0, ring1, prog, CT, NS, NC);
}